// Round 4
// baseline (353.318 us; speedup 1.0000x reference)
//
#include <hip/hip_runtime.h>

using u8  = unsigned char;
using u16 = unsigned short;
using u32 = unsigned int;
typedef __attribute__((ext_vector_type(8))) short short8;   // 8 bf16 (MFMA A/B frag)
typedef __attribute__((ext_vector_type(4))) float f32x4;    // MFMA C/D frag

#define CAPL 384   // per-row candidate list capacity (expected ~187, max ~240)
#define QMIN 64    // static screen: q = round(32*v) >= 64  <=>  v >= 2.0

__device__ __forceinline__ u16 f2bf(float f) {
    union { float f; u32 i; } c; c.f = f;
    u32 u = c.i + 0x7FFFu + ((c.i >> 16) & 1u);   // RNE; inputs are finite
    return (u16)(u >> 16);
}

// ---------------------------------------------------------------------------
// Kernel 0: Ap = bf16(x - b_dec), Wb = bf16(W_enc), zero per-row counters
// ---------------------------------------------------------------------------
__global__ __launch_bounds__(256) void prep_convert(const float* __restrict__ x,
                                                    const float* __restrict__ b_dec,
                                                    const float* __restrict__ W_enc,
                                                    u16* __restrict__ Ap,
                                                    u16* __restrict__ Wb,
                                                    u32* __restrict__ cnt) {
    int i = blockIdx.x * 256 + threadIdx.x;     // grid covers 3*2^20 exactly
    if (i < 4096) cnt[i] = 0;
    if (i < 4096 * 256) {
        Ap[i] = f2bf(x[i] - b_dec[i & 255]);
    } else {
        int j = i - 4096 * 256;                 // < 2*2^20
        Wb[j] = f2bf(W_enc[j]);
    }
}

// ---------------------------------------------------------------------------
// Kernel 1: encode GEMM; epilogue emits candidates (q >= QMIN) to per-row
// compact lists instead of materializing the 32 MB pre-act array.
// M=4096, N=8192, K=256. NT, 128x128 tile, 4 waves of 64x64, 16x16x32 MFMA.
// ---------------------------------------------------------------------------
__global__ __launch_bounds__(256) void encode_gemm(const u16* __restrict__ A,
                                                   const u16* __restrict__ W,
                                                   const float* __restrict__ b_enc,
                                                   u32* __restrict__ cnt,
                                                   u32* __restrict__ list) {
    const int lane = threadIdx.x & 63;
    const int wave = threadIdx.x >> 6;
    const int wm = wave & 1, wn = wave >> 1;
    const int m0 = blockIdx.y * 128 + wm * 64;
    const int n0 = blockIdx.x * 128 + wn * 64;
    const int r15 = lane & 15;            // m (A) / n (B) within 16-frag
    const int kq  = (lane >> 4) * 8;      // k offset within K=32 chunk

    f32x4 acc[4][4] = {};
    const u16* Abase = A + (size_t)(m0 + r15) * 256 + kq;
    const u16* Wbase = W + (size_t)(n0 + r15) * 256 + kq;

    for (int k0 = 0; k0 < 256; k0 += 32) {
        short8 a[4], b[4];
#pragma unroll
        for (int i = 0; i < 4; i++)
            a[i] = *(const short8*)(Abase + i * 16 * 256 + k0);
#pragma unroll
        for (int j = 0; j < 4; j++)
            b[j] = *(const short8*)(Wbase + j * 16 * 256 + k0);
#pragma unroll
        for (int i = 0; i < 4; i++)
#pragma unroll
            for (int j = 0; j < 4; j++)
                acc[i][j] = __builtin_amdgcn_mfma_f32_16x16x32_bf16(a[i], b[j], acc[i][j], 0, 0, 0);
    }

    // C/D layout: col(n) = lane&15, row(m) = (lane>>4)*4 + reg   [m89-verified]
#pragma unroll
    for (int j = 0; j < 4; j++) {
        int n = n0 + j * 16 + r15;
        float bias = b_enc[n];
#pragma unroll
        for (int i = 0; i < 4; i++) {
            int mrow = m0 + i * 16 + (lane >> 4) * 4;
#pragma unroll
            for (int rq = 0; rq < 4; rq++) {
                float v = acc[i][j][rq] + bias;
                int q = (int)(v * 32.f + 0.5f);   // v<=0 -> q<=0
                if (q > 255) q = 255;
                if (q >= QMIN) {
                    int row = mrow + rq;
                    u32 p = atomicAdd(&cnt[row], 1u);
                    if (p < CAPL) list[(size_t)row * CAPL + p] = ((u32)n << 8) | (u32)q;
                }
            }
        }
    }
}

// ---------------------------------------------------------------------------
// Kernel 2: per row — read candidate list, hist over candidates, t32 via
// suffix scan, exact refine {q >= t32-2}, exact top-32 (val desc, idx asc),
// fp32 decode. Guaranteed-exact fallback if screen invalid (never expected).
// ---------------------------------------------------------------------------
__global__ __launch_bounds__(256) void select_decode(const u32* __restrict__ cnt,
                                                     const u32* __restrict__ list,
                                                     const float* __restrict__ x,
                                                     const float* __restrict__ W_enc,
                                                     const float* __restrict__ b_enc,
                                                     const float* __restrict__ W_dec,
                                                     const float* __restrict__ b_dec,
                                                     float* __restrict__ out) {
    const int r    = blockIdx.x;
    const int tid  = threadIdx.x;
    const int lane = tid & 63;
    const int wave = tid >> 6;
    const int grp  = tid >> 4;     // 16 groups of 16 lanes (refine)
    const int l16  = tid & 15;

    __shared__ float s_sae[256];
    __shared__ u32   hist[256];
    __shared__ int   wtot[4];
    __shared__ int   s_t32;
    __shared__ int   cidx[CAPL];
    __shared__ int   cq[CAPL];
    __shared__ float cval[CAPL];
    __shared__ float sel_val[32];
    __shared__ int   sel_idx[32];
    __shared__ float red_v[256];
    __shared__ int   red_i[256];

    s_sae[tid] = x[(size_t)r * 256 + tid] - b_dec[tid];
    hist[tid] = 0;
    if (tid == 0) s_t32 = -1;
    if (tid < 32) { sel_val[tid] = 0.f; sel_idx[tid] = 0; }
    __syncthreads();

    const int m_all = (int)cnt[r];
    const int m = m_all < CAPL ? m_all : CAPL;

    // --- load candidate list, histogram q ------------------------------------
    for (int i = tid; i < m; i += 256) {
        u32 p = list[(size_t)r * CAPL + i];
        int q = (int)(p & 255u);
        cq[i] = q; cidx[i] = (int)(p >> 8);
        atomicAdd(&hist[q], 1u);
    }
    __syncthreads();

    // --- suffix scan: t32 = max{b : count(q >= b) >= 32} ---------------------
    {
        int c = (int)hist[tid];
        int s = c;
#pragma unroll
        for (int off = 1; off < 64; off <<= 1) {
            int v = __shfl_down(s, off);
            if (lane + off < 64) s += v;
        }
        if (lane == 0) wtot[wave] = s;
        __syncthreads();
        int hisum = 0;
        for (int ww = wave + 1; ww < 4; ww++) hisum += wtot[ww];
        int S = s + hisum;
        if (S >= 32 && (S - c) < 32) s_t32 = tid;   // unique transition bin
    }
    __syncthreads();

    // valid screen needs: no list overflow, and t32-2 >= QMIN (membership proof)
    const bool fb = (m_all > CAPL) || (s_t32 < QMIN + 2);

    if (!fb) {
        const int qref = s_t32 - 2;   // true top-32 provably within {q >= qref}

        // --- exact refine (fp64): one 16-lane group per candidate -----------
        for (int cc = grp; cc < m; cc += 16) {
            if (cq[cc] < qref) continue;          // uniform within group
            int idx = cidx[cc];
            const float4* wr = (const float4*)(W_enc + (size_t)idx * 256 + l16 * 16);
            double s = 0.0;
#pragma unroll
            for (int u = 0; u < 4; u++) {
                float4 wv = wr[u];
                const float* sp = &s_sae[l16 * 16 + u * 4];
                s += (double)wv.x * (double)sp[0] + (double)wv.y * (double)sp[1]
                   + (double)wv.z * (double)sp[2] + (double)wv.w * (double)sp[3];
            }
#pragma unroll
            for (int off = 8; off; off >>= 1) s += __shfl_down(s, off, 16);
            if (l16 == 0) {
                float f = (float)(s + (double)b_enc[idx]);
                cval[cc] = f > 0.f ? f : 0.f;
            }
        }
        __syncthreads();

        // --- exact top-32 among refined by (val desc, idx asc) --------------
        for (int i = tid; i < m; i += 256) {
            if (cq[i] < qref) continue;
            float vi = cval[i];
            int   ii = cidx[i];
            int rank = 0;
            for (int j = 0; j < m; j++) {
                if (cq[j] < qref) continue;
                float vj = cval[j];
                rank += (vj > vi) || (vj == vi && cidx[j] < ii);
            }
            if (rank < 32) { sel_val[rank] = vi; sel_idx[rank] = ii; }
        }
        __syncthreads();
    } else {
        // --- guaranteed-exact fallback: full-row top-32 from scratch --------
        // Register-light (recomputes dots); slow but never expected to run.
        u32 taken = 0;
        for (int k = 0; k < 32; k++) {
            float bv = -1.f; int bi = 1 << 30;
            for (int j = 0; j < 32; j++) {
                if ((taken >> j) & 1u) continue;
                int h = tid + 256 * j;
                const float4* wr = (const float4*)(W_enc + (size_t)h * 256);
                double s = 0.0;
                for (int u = 0; u < 64; u++) {
                    float4 wv = wr[u];
                    const float* sp = &s_sae[u * 4];
                    s += (double)wv.x * (double)sp[0] + (double)wv.y * (double)sp[1]
                       + (double)wv.z * (double)sp[2] + (double)wv.w * (double)sp[3];
                }
                float v = (float)(s + (double)b_enc[h]);
                v = v > 0.f ? v : 0.f;
                if (v > bv) { bv = v; bi = h; }   // j asc => smallest idx on tie
            }
            red_v[tid] = bv; red_i[tid] = bi;
            __syncthreads();
            for (int off = 128; off; off >>= 1) {
                if (tid < off) {
                    float v2 = red_v[tid + off]; int i2 = red_i[tid + off];
                    if (v2 > red_v[tid] || (v2 == red_v[tid] && i2 < red_i[tid])) {
                        red_v[tid] = v2; red_i[tid] = i2;
                    }
                }
                __syncthreads();
            }
            int win = red_i[0];
            if (tid == 0) { sel_val[k] = red_v[0]; sel_idx[k] = win; }
            if ((win & 255) == tid) taken |= 1u << (win >> 8);
            __syncthreads();
        }
    }

    // --- decode: out[r] = b_dec + sum_k z_k * W_dec[idx_k] (fp32) -----------
    float acc = b_dec[tid];
#pragma unroll 8
    for (int k = 0; k < 32; k++)
        acc += sel_val[k] * W_dec[(size_t)sel_idx[k] * 256 + tid];  // coalesced 1KB row
    out[(size_t)r * 256 + tid] = acc;
}

// ---------------------------------------------------------------------------
extern "C" void kernel_launch(void* const* d_in, const int* in_sizes, int n_in,
                              void* d_out, int out_size, void* d_ws, size_t ws_size,
                              hipStream_t stream) {
    const float* x     = (const float*)d_in[0];   // [4096,256] f32
    const float* W_enc = (const float*)d_in[1];   // [8192,256] f32
    const float* b_enc = (const float*)d_in[2];   // [8192]     f32
    const float* W_dec = (const float*)d_in[3];   // [8192,256] f32
    const float* b_dec = (const float*)d_in[4];   // [256]      f32
    float* out = (float*)d_out;                   // [4096,256] f32

    u32* cnt  = (u32*)d_ws;                       // 16 KB per-row counters
    u32* list = cnt + 4096;                       // 6 MB candidate lists
    u16* Ap   = (u16*)(list + (size_t)4096 * CAPL);  // 2 MB bf16(x - b_dec)
    u16* Wb   = Ap + (size_t)4096 * 256;             // 4 MB bf16(W_enc)

    prep_convert<<<12288, 256, 0, stream>>>(x, b_dec, W_enc, Ap, Wb, cnt);
    encode_gemm<<<dim3(64, 32), 256, 0, stream>>>(Ap, Wb, b_enc, cnt, list);
    select_decode<<<4096, 256, 0, stream>>>(cnt, list, x, W_enc, b_enc, W_dec, b_dec, out);
}

// Round 5
// 265.965 us; speedup vs baseline: 1.3284x; 1.3284x over previous
//
#include <hip/hip_runtime.h>

using u8  = unsigned char;
using u16 = unsigned short;
using u32 = unsigned int;
typedef __attribute__((ext_vector_type(8))) short short8;   // 8 bf16 (MFMA A/B frag)
typedef __attribute__((ext_vector_type(4))) float f32x4;    // MFMA C/D frag

#define CAPL 384   // per-row candidate list capacity (expected ~193)
#define QMIN 64    // static screen: q = round(32*v) >= 64  <=>  v >= 2.0
#define ECAP 1024  // per-block LDS emission buffer (expected ~386)

__device__ __forceinline__ u16 f2bf(float f) {
    union { float f; u32 i; } c; c.f = f;
    u32 u = c.i + 0x7FFFu + ((c.i >> 16) & 1u);   // RNE; inputs are finite
    return (u16)(u >> 16);
}

// ---------------------------------------------------------------------------
// Kernel 0: Ap = bf16(x - b_dec), Wb = bf16(W_enc), zero per-row counters
// ---------------------------------------------------------------------------
__global__ __launch_bounds__(256) void prep_convert(const float* __restrict__ x,
                                                    const float* __restrict__ b_dec,
                                                    const float* __restrict__ W_enc,
                                                    u16* __restrict__ Ap,
                                                    u16* __restrict__ Wb,
                                                    u32* __restrict__ cnt) {
    int i = blockIdx.x * 256 + threadIdx.x;     // grid covers 3*2^20 exactly
    if (i < 4096) cnt[i] = 0;
    if (i < 4096 * 256) {
        Ap[i] = f2bf(x[i] - b_dec[i & 255]);
    } else {
        int j = i - 4096 * 256;                 // < 2*2^20
        Wb[j] = f2bf(W_enc[j]);
    }
}

// ---------------------------------------------------------------------------
// Kernel 1: encode GEMM; epilogue emits candidates (q >= QMIN) via
// LDS-aggregated per-row lists: block buffer -> per-row offsets -> ONE
// global atomic per (row, block) -> contiguous slot writes.
// M=4096, N=8192, K=256. NT, 128x128 tile, 4 waves of 64x64, 16x16x32 MFMA.
// ---------------------------------------------------------------------------
__global__ __launch_bounds__(256) void encode_gemm(const u16* __restrict__ A,
                                                   const u16* __restrict__ W,
                                                   const float* __restrict__ b_enc,
                                                   u32* __restrict__ cnt,
                                                   u32* __restrict__ list) {
    const int tid  = threadIdx.x;
    const int lane = tid & 63;
    const int wave = tid >> 6;
    const int wm = wave & 1, wn = wave >> 1;
    const int bm0 = blockIdx.y * 128;             // block row base
    const int m0  = bm0 + wm * 64;
    const int n0  = blockIdx.x * 128 + wn * 64;
    const int r15 = lane & 15;            // m (A) / n (B) within 16-frag
    const int kq  = (lane >> 4) * 8;      // k offset within K=32 chunk

    __shared__ u32 s_n;
    __shared__ u32 s_ebuf[ECAP];   // entry: (rowl<<21)|(n<<8)|q
    __shared__ u8  s_eofs[ECAP];   // within-(row,block) offset (<=128, fits u8)
    __shared__ u32 l_cnt[128];
    __shared__ u32 l_base[128];

    if (tid == 0) s_n = 0;
    if (tid < 128) l_cnt[tid] = 0;
    __syncthreads();

    f32x4 acc[4][4] = {};
    const u16* Abase = A + (size_t)(m0 + r15) * 256 + kq;
    const u16* Wbase = W + (size_t)(n0 + r15) * 256 + kq;

    for (int k0 = 0; k0 < 256; k0 += 32) {
        short8 a[4], b[4];
#pragma unroll
        for (int i = 0; i < 4; i++)
            a[i] = *(const short8*)(Abase + i * 16 * 256 + k0);
#pragma unroll
        for (int j = 0; j < 4; j++)
            b[j] = *(const short8*)(Wbase + j * 16 * 256 + k0);
#pragma unroll
        for (int i = 0; i < 4; i++)
#pragma unroll
            for (int j = 0; j < 4; j++)
                acc[i][j] = __builtin_amdgcn_mfma_f32_16x16x32_bf16(a[i], b[j], acc[i][j], 0, 0, 0);
    }

    // C/D layout: col(n) = lane&15, row(m) = (lane>>4)*4 + reg   [m89-verified]
#pragma unroll
    for (int j = 0; j < 4; j++) {
        int n = n0 + j * 16 + r15;
        float bias = b_enc[n];
#pragma unroll
        for (int i = 0; i < 4; i++) {
            int rowl0 = wm * 64 + i * 16 + (lane >> 4) * 4;   // local row, 0..127
#pragma unroll
            for (int rq = 0; rq < 4; rq++) {
                float v = acc[i][j][rq] + bias;
                int q = (int)(v * 32.f + 0.5f);   // v<=0 -> q<=0
                if (q > 255) q = 255;
                if (q >= QMIN) {
                    u32 rowl = (u32)(rowl0 + rq);
                    u32 e = (rowl << 21) | ((u32)n << 8) | (u32)q;
                    u32 p = atomicAdd(&s_n, 1u);
                    if (p < ECAP) {
                        s_ebuf[p] = e;
                    } else {                       // rare spill: direct global
                        u32 g = atomicAdd(&cnt[bm0 + rowl], 1u);
                        if (g < CAPL) list[(size_t)(bm0 + rowl) * CAPL + g] = e & 0x1FFFFFu;
                    }
                }
            }
        }
    }
    __syncthreads();

    int ne = (int)s_n; if (ne > ECAP) ne = ECAP;
    // Phase A: within-row offsets via LDS atomics
    for (int i = tid; i < ne; i += 256)
        s_eofs[i] = (u8)atomicAdd(&l_cnt[s_ebuf[i] >> 21], 1u);
    __syncthreads();
    // Phase B: one global reservation per (row, block)
    if (tid < 128 && l_cnt[tid] > 0)
        l_base[tid] = atomicAdd(&cnt[bm0 + tid], l_cnt[tid]);
    __syncthreads();
    // Phase C: contiguous slot writes
    for (int i = tid; i < ne; i += 256) {
        u32 e = s_ebuf[i];
        u32 rowl = e >> 21;
        u32 slot = l_base[rowl] + (u32)s_eofs[i];
        if (slot < CAPL) list[(size_t)(bm0 + rowl) * CAPL + slot] = e & 0x1FFFFFu;
    }
}

// ---------------------------------------------------------------------------
// Kernel 2: per row — read candidate list, hist over candidates, t32 via
// suffix scan, exact refine {q >= t32-2}, exact top-32 (val desc, idx asc),
// fp32 decode. Guaranteed-exact fallback if screen invalid (never expected).
// ---------------------------------------------------------------------------
__global__ __launch_bounds__(256) void select_decode(const u32* __restrict__ cnt,
                                                     const u32* __restrict__ list,
                                                     const float* __restrict__ x,
                                                     const float* __restrict__ W_enc,
                                                     const float* __restrict__ b_enc,
                                                     const float* __restrict__ W_dec,
                                                     const float* __restrict__ b_dec,
                                                     float* __restrict__ out) {
    const int r    = blockIdx.x;
    const int tid  = threadIdx.x;
    const int lane = tid & 63;
    const int wave = tid >> 6;
    const int grp  = tid >> 4;     // 16 groups of 16 lanes (refine)
    const int l16  = tid & 15;

    __shared__ float s_sae[256];
    __shared__ u32   hist[256];
    __shared__ int   wtot[4];
    __shared__ int   s_t32;
    __shared__ int   cidx[CAPL];
    __shared__ int   cq[CAPL];
    __shared__ float cval[CAPL];
    __shared__ float sel_val[32];
    __shared__ int   sel_idx[32];
    __shared__ float red_v[256];
    __shared__ int   red_i[256];

    s_sae[tid] = x[(size_t)r * 256 + tid] - b_dec[tid];
    hist[tid] = 0;
    if (tid == 0) s_t32 = -1;
    if (tid < 32) { sel_val[tid] = 0.f; sel_idx[tid] = 0; }
    __syncthreads();

    const int m_all = (int)cnt[r];
    const int m = m_all < CAPL ? m_all : CAPL;

    // --- load candidate list, histogram q ------------------------------------
    for (int i = tid; i < m; i += 256) {
        u32 p = list[(size_t)r * CAPL + i];
        int q = (int)(p & 255u);
        cq[i] = q; cidx[i] = (int)(p >> 8);
        atomicAdd(&hist[q], 1u);
    }
    __syncthreads();

    // --- suffix scan: t32 = max{b : count(q >= b) >= 32} ---------------------
    {
        int c = (int)hist[tid];
        int s = c;
#pragma unroll
        for (int off = 1; off < 64; off <<= 1) {
            int v = __shfl_down(s, off);
            if (lane + off < 64) s += v;
        }
        if (lane == 0) wtot[wave] = s;
        __syncthreads();
        int hisum = 0;
        for (int ww = wave + 1; ww < 4; ww++) hisum += wtot[ww];
        int S = s + hisum;
        if (S >= 32 && (S - c) < 32) s_t32 = tid;   // unique transition bin
    }
    __syncthreads();

    // valid screen needs: no list overflow, and t32-2 >= QMIN (membership proof)
    const bool fb = (m_all > CAPL) || (s_t32 < QMIN + 2);

    if (!fb) {
        const int qref = s_t32 - 2;   // true top-32 provably within {q >= qref}

        // --- exact refine (fp64): one 16-lane group per candidate -----------
        for (int cc = grp; cc < m; cc += 16) {
            if (cq[cc] < qref) continue;          // uniform within group
            int idx = cidx[cc];
            const float4* wr = (const float4*)(W_enc + (size_t)idx * 256 + l16 * 16);
            double s = 0.0;
#pragma unroll
            for (int u = 0; u < 4; u++) {
                float4 wv = wr[u];
                const float* sp = &s_sae[l16 * 16 + u * 4];
                s += (double)wv.x * (double)sp[0] + (double)wv.y * (double)sp[1]
                   + (double)wv.z * (double)sp[2] + (double)wv.w * (double)sp[3];
            }
#pragma unroll
            for (int off = 8; off; off >>= 1) s += __shfl_down(s, off, 16);
            if (l16 == 0) {
                float f = (float)(s + (double)b_enc[idx]);
                cval[cc] = f > 0.f ? f : 0.f;
            }
        }
        __syncthreads();

        // --- exact top-32 among refined by (val desc, idx asc) --------------
        for (int i = tid; i < m; i += 256) {
            if (cq[i] < qref) continue;
            float vi = cval[i];
            int   ii = cidx[i];
            int rank = 0;
            for (int j = 0; j < m; j++) {
                if (cq[j] < qref) continue;
                float vj = cval[j];
                rank += (vj > vi) || (vj == vi && cidx[j] < ii);
            }
            if (rank < 32) { sel_val[rank] = vi; sel_idx[rank] = ii; }
        }
        __syncthreads();
    } else {
        // --- guaranteed-exact fallback: full-row top-32 from scratch --------
        u32 taken = 0;
        for (int k = 0; k < 32; k++) {
            float bv = -1.f; int bi = 1 << 30;
            for (int j = 0; j < 32; j++) {
                if ((taken >> j) & 1u) continue;
                int h = tid + 256 * j;
                const float4* wr = (const float4*)(W_enc + (size_t)h * 256);
                double s = 0.0;
                for (int u = 0; u < 64; u++) {
                    float4 wv = wr[u];
                    const float* sp = &s_sae[u * 4];
                    s += (double)wv.x * (double)sp[0] + (double)wv.y * (double)sp[1]
                       + (double)wv.z * (double)sp[2] + (double)wv.w * (double)sp[3];
                }
                float v = (float)(s + (double)b_enc[h]);
                v = v > 0.f ? v : 0.f;
                if (v > bv) { bv = v; bi = h; }   // j asc => smallest idx on tie
            }
            red_v[tid] = bv; red_i[tid] = bi;
            __syncthreads();
            for (int off = 128; off; off >>= 1) {
                if (tid < off) {
                    float v2 = red_v[tid + off]; int i2 = red_i[tid + off];
                    if (v2 > red_v[tid] || (v2 == red_v[tid] && i2 < red_i[tid])) {
                        red_v[tid] = v2; red_i[tid] = i2;
                    }
                }
                __syncthreads();
            }
            int win = red_i[0];
            if (tid == 0) { sel_val[k] = red_v[0]; sel_idx[k] = win; }
            if ((win & 255) == tid) taken |= 1u << (win >> 8);
            __syncthreads();
        }
    }

    // --- decode: out[r] = b_dec + sum_k z_k * W_dec[idx_k] (fp32) -----------
    float acc = b_dec[tid];
#pragma unroll 8
    for (int k = 0; k < 32; k++)
        acc += sel_val[k] * W_dec[(size_t)sel_idx[k] * 256 + tid];  // coalesced 1KB row
    out[(size_t)r * 256 + tid] = acc;
}

// ---------------------------------------------------------------------------
extern "C" void kernel_launch(void* const* d_in, const int* in_sizes, int n_in,
                              void* d_out, int out_size, void* d_ws, size_t ws_size,
                              hipStream_t stream) {
    const float* x     = (const float*)d_in[0];   // [4096,256] f32
    const float* W_enc = (const float*)d_in[1];   // [8192,256] f32
    const float* b_enc = (const float*)d_in[2];   // [8192]     f32
    const float* W_dec = (const float*)d_in[3];   // [8192,256] f32
    const float* b_dec = (const float*)d_in[4];   // [256]      f32
    float* out = (float*)d_out;                   // [4096,256] f32

    u32* cnt  = (u32*)d_ws;                       // 16 KB per-row counters
    u32* list = cnt + 4096;                       // 6 MB candidate lists
    u16* Ap   = (u16*)(list + (size_t)4096 * CAPL);  // 2 MB bf16(x - b_dec)
    u16* Wb   = Ap + (size_t)4096 * 256;             // 4 MB bf16(W_enc)

    prep_convert<<<12288, 256, 0, stream>>>(x, b_dec, W_enc, Ap, Wb, cnt);
    encode_gemm<<<dim3(64, 32), 256, 0, stream>>>(Ap, Wb, b_enc, cnt, list);
    select_decode<<<4096, 256, 0, stream>>>(cnt, list, x, W_enc, b_enc, W_dec, b_dec, out);
}